// Round 1
// baseline (371.140 us; speedup 1.0000x reference)
//
#include <hip/hip_runtime.h>
#include <stdint.h>

#define M_DIM 8192   // K of the Gram GEMM (rows of input A)
#define N_DIM 4096   // output is N_DIM x N_DIM
#define BM 128
#define BK 32

typedef __attribute__((ext_vector_type(4))) float f32x4;
typedef __attribute__((ext_vector_type(8))) short bf16x8;

// fp32 -> bf16 round-to-nearest-even (inputs are finite normals)
__device__ __forceinline__ ushort f2bf(float x) {
  union { float f; uint32_t u; } v;
  v.f = x;
  uint32_t r = (v.u + 0x7fffu + ((v.u >> 16) & 1u)) >> 16;
  return (ushort)r;
}

// async global->LDS, 16B per lane. LDS dest must be wave-uniform base + lane*16.
__device__ __forceinline__ void gl_lds16(const ushort* g, ushort* l) {
  __builtin_amdgcn_global_load_lds(
      (const __attribute__((address_space(1))) void*)g,
      (__attribute__((address_space(3))) void*)l,
      16, 0, 0);
}

// ---------------- Kernel 1: A[M][N] fp32 -> At[N][M] bf16 (transpose+convert)
__global__ __launch_bounds__(256) void transpose_convert(
    const float* __restrict__ A, ushort* __restrict__ At) {
  __shared__ ushort tile[64][66];  // 66: 33-dword row stride -> conflict-free
  const int bm = blockIdx.x % (M_DIM / 64);
  const int bn = blockIdx.x / (M_DIM / 64);
  const int m0 = bm * 64, n0 = bn * 64;
  const int t = threadIdx.x;
  const int tr = t >> 4;          // 0..15
  const int tc = (t & 15) << 2;   // 0,4,...,60

#pragma unroll
  for (int p = 0; p < 4; ++p) {
    const int r = p * 16 + tr;  // m within tile
    const float4 v = *reinterpret_cast<const float4*>(
        &A[(size_t)(m0 + r) * N_DIM + (n0 + tc)]);
    tile[tc + 0][r] = f2bf(v.x);
    tile[tc + 1][r] = f2bf(v.y);
    tile[tc + 2][r] = f2bf(v.z);
    tile[tc + 3][r] = f2bf(v.w);
  }
  __syncthreads();
#pragma unroll
  for (int p = 0; p < 4; ++p) {
    const int rn = p * 16 + tr;  // n within tile
    ushort4 o;
    o.x = tile[rn][tc + 0];
    o.y = tile[rn][tc + 1];
    o.z = tile[rn][tc + 2];
    o.w = tile[rn][tc + 3];
    *reinterpret_cast<ushort4*>(
        &At[(size_t)(n0 + rn) * M_DIM + (m0 + tc)]) = o;
  }
}

// ---------------- Kernel 2: C = At * At^T (Gram), upper-tri blocks + mirror
// m97 structure: 128x128 tile, BK=32, 4 waves (2x2), global_load_lds width 16.
__global__ __launch_bounds__(256) void gram_mfma(
    const ushort* __restrict__ At, float* __restrict__ C) {
  __shared__ ushort Asub[BM * BK];  // 8 KiB
  __shared__ ushort Bsub[BM * BK];  // 8 KiB

  // decode blockIdx -> upper-triangular tile (bi <= bj)
  const int nb = N_DIM / BM;  // 32
  int rem = (int)blockIdx.x, bi = 0;
  while (rem >= nb - bi) { rem -= nb - bi; ++bi; }
  const int bj = bi + rem;

  const int tid = (int)threadIdx.x;
  const int lane = tid & 63;
  const int wave = tid >> 6;
  const int wr = wave >> 1, wc = wave & 1;
  const int fr = lane & 15, fq = lane >> 4;

  // staging: thread t covers LDS bytes [t*16, t*16+16) = row t/4, k-chunk (t%4)*8
  const int srow = tid >> 2;
  const int scol = (tid & 3) << 3;
  const ushort* ga = At + (size_t)(bi * BM + srow) * M_DIM + scol;
  const ushort* gb = At + (size_t)(bj * BM + srow) * M_DIM + scol;
  ushort* la = Asub + tid * 8;
  ushort* lb = Bsub + tid * 8;

  f32x4 acc[4][4] = {};

  for (int k0 = 0; k0 < M_DIM; k0 += BK) {
    __syncthreads();  // previous compute done before overwrite
    gl_lds16(ga + k0, la);
    gl_lds16(ga + (size_t)64 * M_DIM + k0, la + 2048);  // rows 64..127
    gl_lds16(gb + k0, lb);
    gl_lds16(gb + (size_t)64 * M_DIM + k0, lb + 2048);
    __syncthreads();  // drains vmcnt -> staging visible

    bf16x8 a[4], b[4];
#pragma unroll
    for (int mi = 0; mi < 4; ++mi)
      a[mi] = *reinterpret_cast<const bf16x8*>(
          &Asub[(wr * 64 + mi * 16 + fr) * BK + fq * 8]);
#pragma unroll
    for (int nj = 0; nj < 4; ++nj)
      b[nj] = *reinterpret_cast<const bf16x8*>(
          &Bsub[(wc * 64 + nj * 16 + fr) * BK + fq * 8]);

#pragma unroll
    for (int mi = 0; mi < 4; ++mi)
#pragma unroll
      for (int nj = 0; nj < 4; ++nj)
        acc[mi][nj] = __builtin_amdgcn_mfma_f32_16x16x32_bf16(
            a[mi], b[nj], acc[mi][nj], 0, 0, 0);
  }

  // epilogue: direct store C[i][j] + mirrored C[j][i] (float4 along mirror row)
  const int rb = bi * BM + wr * 64;
  const int cb = bj * BM + wc * 64;
#pragma unroll
  for (int mi = 0; mi < 4; ++mi) {
#pragma unroll
    for (int nj = 0; nj < 4; ++nj) {
      const int r0 = rb + mi * 16 + fq * 4;
      const int c = cb + nj * 16 + fr;
      const f32x4 v = acc[mi][nj];
#pragma unroll
      for (int r = 0; r < 4; ++r)
        C[(size_t)(r0 + r) * N_DIM + c] = v[r];
      if (bi != bj)
        *reinterpret_cast<f32x4*>(&C[(size_t)c * N_DIM + r0]) = v;
    }
  }
}

extern "C" void kernel_launch(void* const* d_in, const int* in_sizes, int n_in,
                              void* d_out, int out_size, void* d_ws, size_t ws_size,
                              hipStream_t stream) {
  const float* A = (const float*)d_in[0];
  float* C = (float*)d_out;
  ushort* At = (ushort*)d_ws;  // 4096*8192*2 = 64 MiB

  // 1) transpose + convert
  transpose_convert<<<dim3((M_DIM / 64) * (N_DIM / 64)), 256, 0, stream>>>(A, At);

  // 2) Gram GEMM over upper-triangular 128x128 tiles
  const int nb = N_DIM / BM;                 // 32
  const int ntiles = nb * (nb + 1) / 2;      // 528
  gram_mfma<<<dim3(ntiles), 256, 0, stream>>>(At, C);
}

// Round 2
// 263.970 us; speedup vs baseline: 1.4060x; 1.4060x over previous
//
#include <hip/hip_runtime.h>
#include <stdint.h>

#define M_DIM 8192   // K of the Gram GEMM (rows of input A)
#define N_DIM 4096   // output is N_DIM x N_DIM
#define BK 32        // K per tile
#define NT (M_DIM / BK)  // 256 K-tiles

typedef __attribute__((ext_vector_type(4))) float f32x4;
typedef __attribute__((ext_vector_type(8))) short bf16x8;

// fp32 -> bf16 round-to-nearest-even
__device__ __forceinline__ ushort f2bf(float x) {
  union { float f; uint32_t u; } v;
  v.f = x;
  uint32_t r = (v.u + 0x7fffu + ((v.u >> 16) & 1u)) >> 16;
  return (ushort)r;
}

// async global->LDS, 16B/lane; LDS dest must be wave-uniform base + lane*16.
__device__ __forceinline__ void gl_lds16b(const char* g, char* l) {
  __builtin_amdgcn_global_load_lds(
      (const __attribute__((address_space(1))) void*)g,
      (__attribute__((address_space(3))) void*)l, 16, 0, 0);
}

// involutive LDS swizzle: XOR row bits 1-3 (byte bits 7-9) into chunk bits 4-6.
// 16B-chunk safe (bits<4 untouched); spreads 16-row stride-64B reads to 2-way.
__device__ __forceinline__ int swz(int d) { return d ^ (((d >> 7) & 7) << 4); }

// ---------------- Kernel 1: A[M][N] fp32 -> At[N][M] bf16 (transpose+convert)
__global__ __launch_bounds__(256) void transpose_convert(
    const float* __restrict__ A, ushort* __restrict__ At) {
  __shared__ ushort tile[64][66];
  const int bm = blockIdx.x % (M_DIM / 64);
  const int bn = blockIdx.x / (M_DIM / 64);
  const int m0 = bm * 64, n0 = bn * 64;
  const int t = threadIdx.x;
  const int tr = t >> 4;
  const int tc = (t & 15) << 2;

#pragma unroll
  for (int p = 0; p < 4; ++p) {
    const int r = p * 16 + tr;
    const float4 v = *reinterpret_cast<const float4*>(
        &A[(size_t)(m0 + r) * N_DIM + (n0 + tc)]);
    tile[tc + 0][r] = f2bf(v.x);
    tile[tc + 1][r] = f2bf(v.y);
    tile[tc + 2][r] = f2bf(v.z);
    tile[tc + 3][r] = f2bf(v.w);
  }
  __syncthreads();
#pragma unroll
  for (int p = 0; p < 4; ++p) {
    const int rn = p * 16 + tr;
    ushort4 o;
    o.x = tile[rn][tc + 0];
    o.y = tile[rn][tc + 1];
    o.z = tile[rn][tc + 2];
    o.w = tile[rn][tc + 3];
    *reinterpret_cast<ushort4*>(
        &At[(size_t)(n0 + rn) * M_DIM + (m0 + tc)]) = o;
  }
}

// ---------------- Kernel 2: 256x256-tile 8-phase Gram GEMM
// 8 waves (2Mx4N), BK=32 per K-tile, 4 LDS buffers, counted vmcnt(8),
// setprio around MFMA clusters, XCD-swizzled grid, swizzled LDS.
__global__ __launch_bounds__(512, 2) void gram8(
    const ushort* __restrict__ At, float* __restrict__ C) {
  __shared__ char smem[131072];  // A: 4 bufs x 16KB | B: 4 bufs x 16KB
  char* As = smem;
  char* Bs = smem + 65536;

  // XCD-aware block swizzle (256 blocks % 8 == 0 -> simple chunked form)
  const int bid = (int)blockIdx.x;
  const int wg = (bid & 7) * 32 + (bid >> 3);
  const int bi = wg >> 4, bj = wg & 15;

  const int t = (int)threadIdx.x;
  const int lane = t & 63, wave = t >> 6;
  const int wr = wave >> 2, wc = wave & 3;   // wave tile: rows wr*128, cols wc*64
  const int fr = lane & 15, fq = lane >> 4;

  // ---- staging precompute: per-thread linear LDS chunk -> pre-swizzled src
  const char* Atb = (const char*)At;
  const size_t MB = (size_t)M_DIM * 2;  // bytes per At row
  const int d0 = t * 16;                // load q=0: rows 0..127 of region
  const int d1 = 8192 + t * 16;         // load q=1: rows 128..255
  const int s0 = swz(d0), s1 = swz(d1);
  const char* sA0 = Atb + (size_t)(bi * 256 + (s0 >> 6)) * MB + (s0 & 63);
  const char* sA1 = Atb + (size_t)(bi * 256 + (s1 >> 6)) * MB + (s1 & 63);
  const char* sB0 = Atb + (size_t)(bj * 256 + (s0 >> 6)) * MB + (s0 & 63);
  const char* sB1 = Atb + (size_t)(bj * 256 + (s1 >> 6)) * MB + (s1 & 63);

  // ---- fragment LDS offsets (swizzled), loop-invariant
  int adA[8], adB[4];
#pragma unroll
  for (int m = 0; m < 8; ++m) {
    const int row = wr * 128 + m * 16 + fr;
    adA[m] = swz(row * 64 + fq * 16);
  }
#pragma unroll
  for (int n = 0; n < 4; ++n) {
    const int row = wc * 64 + n * 16 + fr;
    adB[n] = swz(row * 64 + fq * 16);
  }

  f32x4 acc[8][4] = {};

  // ---- prologue: stage K-tiles 0,1,2 (12 loads), wait tile0 (vmcnt(8))
#pragma unroll
  for (int kts = 0; kts < 3; ++kts) {
    const int bb = kts * 16384;
    const size_t ko = (size_t)kts * 64;
    gl_lds16b(sA0 + ko, As + bb + d0);
    gl_lds16b(sA1 + ko, As + bb + d1);
    gl_lds16b(sB0 + ko, Bs + bb + d0);
    gl_lds16b(sB1 + ko, Bs + bb + d1);
  }
  asm volatile("s_waitcnt vmcnt(8)" ::: "memory");
  __builtin_amdgcn_s_barrier();
  asm volatile("" ::: "memory");

  // ---- one K-tile = 2 phases of {ds_read | stage-issue | barrier | MFMA | barrier}
  auto ktile = [&](int kt, bool do_stage, int vmw) __attribute__((always_inline)) {
    const int bb = (kt & 3) * 16384;
    const char* Ab = As + bb;
    const char* Bb = Bs + bb;
    const int sb = ((kt + 3) & 3) * 16384;
    const size_t ko = (size_t)(kt + 3) * 64;

    // --- phase A: read A frags + B[0..1]; stage next A half-tiles
    bf16x8 a[8], bf[4];
#pragma unroll
    for (int m = 0; m < 8; ++m)
      a[m] = *reinterpret_cast<const bf16x8*>(Ab + adA[m]);
    bf[0] = *reinterpret_cast<const bf16x8*>(Bb + adB[0]);
    bf[1] = *reinterpret_cast<const bf16x8*>(Bb + adB[1]);
    if (do_stage) {
      gl_lds16b(sA0 + ko, As + sb + d0);
      gl_lds16b(sA1 + ko, As + sb + d1);
    }
    __builtin_amdgcn_s_barrier();
    asm volatile("" ::: "memory");
    __builtin_amdgcn_s_setprio(1);
#pragma unroll
    for (int m = 0; m < 8; ++m) {
      acc[m][0] = __builtin_amdgcn_mfma_f32_16x16x32_bf16(a[m], bf[0], acc[m][0], 0, 0, 0);
      acc[m][1] = __builtin_amdgcn_mfma_f32_16x16x32_bf16(a[m], bf[1], acc[m][1], 0, 0, 0);
    }
    __builtin_amdgcn_s_setprio(0);
    __builtin_amdgcn_s_barrier();
    asm volatile("" ::: "memory");

    // --- phase B: read B[2..3]; stage next B half-tiles; counted vmcnt
    bf[2] = *reinterpret_cast<const bf16x8*>(Bb + adB[2]);
    bf[3] = *reinterpret_cast<const bf16x8*>(Bb + adB[3]);
    if (do_stage) {
      gl_lds16b(sB0 + ko, Bs + sb + d0);
      gl_lds16b(sB1 + ko, Bs + sb + d1);
    }
    if (vmw == 8)      asm volatile("s_waitcnt vmcnt(8)" ::: "memory");
    else if (vmw == 4) asm volatile("s_waitcnt vmcnt(4)" ::: "memory");
    else if (vmw == 0) asm volatile("s_waitcnt vmcnt(0)" ::: "memory");
    __builtin_amdgcn_s_barrier();
    asm volatile("" ::: "memory");
    __builtin_amdgcn_s_setprio(1);
#pragma unroll
    for (int m = 0; m < 8; ++m) {
      acc[m][2] = __builtin_amdgcn_mfma_f32_16x16x32_bf16(a[m], bf[2], acc[m][2], 0, 0, 0);
      acc[m][3] = __builtin_amdgcn_mfma_f32_16x16x32_bf16(a[m], bf[3], acc[m][3], 0, 0, 0);
    }
    __builtin_amdgcn_s_setprio(0);
    __builtin_amdgcn_s_barrier();
    asm volatile("" ::: "memory");
  };

  for (int kt = 0; kt < NT - 3; ++kt) ktile(kt, true, 8);
  ktile(NT - 3, false, 4);
  ktile(NT - 2, false, 0);
  ktile(NT - 1, false, -1);

  // ---- epilogue: direct fp32 stores (verified C/D map: col=lane&15, row=fq*4+j)
  const int rb = bi * 256 + wr * 128;
  const int cb = bj * 256 + wc * 64;
#pragma unroll
  for (int m = 0; m < 8; ++m) {
    const int r0 = rb + m * 16 + fq * 4;
#pragma unroll
    for (int n = 0; n < 4; ++n) {
      const int c = cb + n * 16 + fr;
#pragma unroll
      for (int j = 0; j < 4; ++j)
        C[(size_t)(r0 + j) * N_DIM + c] = acc[m][n][j];
    }
  }
}

extern "C" void kernel_launch(void* const* d_in, const int* in_sizes, int n_in,
                              void* d_out, int out_size, void* d_ws, size_t ws_size,
                              hipStream_t stream) {
  const float* A = (const float*)d_in[0];
  float* C = (float*)d_out;
  ushort* At = (ushort*)d_ws;  // 4096*8192*2 = 64 MiB

  transpose_convert<<<dim3((M_DIM / 64) * (N_DIM / 64)), 256, 0, stream>>>(A, At);
  gram8<<<dim3(16 * 16), 512, 0, stream>>>(At, C);
}

// Round 3
// 252.409 us; speedup vs baseline: 1.4704x; 1.0458x over previous
//
#include <hip/hip_runtime.h>
#include <stdint.h>

#define M_DIM 8192   // K of the Gram GEMM
#define N_DIM 4096   // output N x N
#define NSTEP (M_DIM / 64)  // 128 K-steps of 64

typedef __attribute__((ext_vector_type(4))) float f32x4;
typedef __attribute__((ext_vector_type(8))) short bf16x8;

__device__ __forceinline__ ushort f2bf(float x) {
  union { float f; uint32_t u; } v;
  v.f = x;
  uint32_t r = (v.u + 0x7fffu + ((v.u >> 16) & 1u)) >> 16;
  return (ushort)r;
}

__device__ __forceinline__ void gl_lds16b(const char* g, char* l) {
  __builtin_amdgcn_global_load_lds(
      (const __attribute__((address_space(1))) void*)g,
      (__attribute__((address_space(3))) void*)l, 16, 0, 0);
}

#define CFENCE asm volatile("" ::: "memory")

// ---------------- Kernel 1: A[M][N] fp32 -> At[N][M] bf16
__global__ __launch_bounds__(256) void transpose_convert(
    const float* __restrict__ A, ushort* __restrict__ At) {
  __shared__ ushort tile[64][66];
  const int bm = blockIdx.x % (M_DIM / 64);
  const int bn = blockIdx.x / (M_DIM / 64);
  const int m0 = bm * 64, n0 = bn * 64;
  const int t = threadIdx.x;
  const int tr = t >> 4;
  const int tc = (t & 15) << 2;
#pragma unroll
  for (int p = 0; p < 4; ++p) {
    const int r = p * 16 + tr;
    const float4 v = *reinterpret_cast<const float4*>(
        &A[(size_t)(m0 + r) * N_DIM + (n0 + tc)]);
    tile[tc + 0][r] = f2bf(v.x);
    tile[tc + 1][r] = f2bf(v.y);
    tile[tc + 2][r] = f2bf(v.z);
    tile[tc + 3][r] = f2bf(v.w);
  }
  __syncthreads();
#pragma unroll
  for (int p = 0; p < 4; ++p) {
    const int rn = p * 16 + tr;
    ushort4 o;
    o.x = tile[rn][tc + 0];
    o.y = tile[rn][tc + 1];
    o.z = tile[rn][tc + 2];
    o.w = tile[rn][tc + 3];
    *reinterpret_cast<ushort4*>(
        &At[(size_t)(n0 + rn) * M_DIM + (m0 + tc)]) = o;
  }
}

// ---------------- Kernel 2: 256x256 tile, BK=64, m201-faithful 4-phase K-step
// LDS per dbuf d (base d*65536): A0 @0, A1 @16384, B0 @32768, B1 @49152
// (region hq*8192 covers 64 global rows each, hq = h*2+q)
__global__ __launch_bounds__(512, 2) void gram8(
    const ushort* __restrict__ At, float* __restrict__ C) {
  __shared__ char smem[131072];

  const int bid = (int)blockIdx.x;
  const int wg = (bid & 7) * 32 + (bid >> 3);  // XCD swizzle (256 % 8 == 0)
  const int bi = wg >> 4, bj = wg & 15;

  const int t = (int)threadIdx.x;
  const int lane = t & 63, wave = t >> 6;
  const int wr = wave >> 2, wc = wave & 3;   // wave tile: rows wr*128, cols wc*64
  const int fr = lane & 15, fq = lane >> 4;

  // ---- LDS read bases. Swizzle: off ^= ((off>>7)&7)<<4; row&7 == fr&7.
  // XOR touches bit6 (the kk bit), so keep separate kk bases.
  const int xorv = (fr & 7) << 4;
  const int colk0 = (fq * 16) ^ xorv;
  const int colk1 = (64 + fq * 16) ^ xorv;   // 64 | fq*16 are disjoint bits
  char* const aK0 = smem + wr * 16384 + fr * 128 + colk0;
  char* const aK1 = smem + wr * 16384 + fr * 128 + colk1;
  char* const bK0 = smem + 32768 + (wc >> 1) * 16384 + ((wc & 1) * 64 + fr) * 128 + colk0;
  char* const bK1 = smem + 32768 + (wc >> 1) * 16384 + ((wc & 1) * 64 + fr) * 128 + colk1;

  // ---- staging source pointers (pre-swizzled global src, linear LDS dest)
  const char* const Atb = (const char*)At;
  const size_t MB = (size_t)M_DIM * 2;
  const int rq = t >> 3;                               // row within 64-row group
  const int cs = ((t & 7) * 16) ^ ((rq & 7) << 4);     // swizzled col byte
  const char* sA[4];
  const char* sB[4];
#pragma unroll
  for (int hq = 0; hq < 4; ++hq) {
    const int grow = hq * 64 + rq;
    sA[hq] = Atb + (size_t)(bi * 256 + grow) * MB + cs;
    sB[hq] = Atb + (size_t)(bj * 256 + grow) * MB + cs;
  }

  bf16x8 a[4][2], b0[2][2], b1[2][2];
  f32x4 acc[8][4] = {};

  // ---- prologue: stage steps 0 (buf0) and 1 (buf1); wait step0
#pragma unroll
  for (int ss = 0; ss < 2; ++ss) {
    const int off = ss * 65536;
#pragma unroll
    for (int hq = 0; hq < 4; ++hq) {
      gl_lds16b(sA[hq] + (size_t)ss * 128, smem + off + hq * 8192 + t * 16);
      gl_lds16b(sB[hq] + (size_t)ss * 128, smem + off + 32768 + hq * 8192 + t * 16);
    }
  }
  asm volatile("s_waitcnt vmcnt(8)" ::: "memory");
  __builtin_amdgcn_s_barrier();
  CFENCE;

#define MFMA16(AM0, NB0, BSET)                                              \
  __builtin_amdgcn_s_setprio(1);                                            \
  _Pragma("unroll") for (int kk = 0; kk < 2; ++kk)                          \
    _Pragma("unroll") for (int m = 0; m < 4; ++m)                           \
      _Pragma("unroll") for (int n = 0; n < 2; ++n)                         \
        acc[(AM0) + m][(NB0) + n] = __builtin_amdgcn_mfma_f32_16x16x32_bf16(\
            a[m][kk], BSET[n][kk], acc[(AM0) + m][(NB0) + n], 0, 0, 0);     \
  __builtin_amdgcn_s_setprio(0);

#define KSTEP(d, s, STG, VMW) do {                                          \
  const int off = (d) * 65536;                                              \
  /* ph1: read A m0-3 (8) + B n0-1 (4); 12 reads -> lgkm throttle */        \
  _Pragma("unroll") for (int m = 0; m < 4; ++m) {                           \
    a[m][0] = *reinterpret_cast<const bf16x8*>(aK0 + off + m * 2048);       \
    a[m][1] = *reinterpret_cast<const bf16x8*>(aK1 + off + m * 2048);       \
  }                                                                         \
  _Pragma("unroll") for (int n = 0; n < 2; ++n) {                           \
    b0[n][0] = *reinterpret_cast<const bf16x8*>(bK0 + off + n * 2048);      \
    b0[n][1] = *reinterpret_cast<const bf16x8*>(bK1 + off + n * 2048);      \
  }                                                                         \
  asm volatile("s_waitcnt lgkmcnt(8)" ::: "memory");                        \
  __builtin_amdgcn_s_barrier();                                             \
  asm volatile("s_waitcnt lgkmcnt(0)" ::: "memory");                        \
  __builtin_amdgcn_sched_barrier(0);                                        \
  MFMA16(0, 0, b0)                                                          \
  __builtin_amdgcn_s_barrier();                                             \
  CFENCE;                                                                   \
  /* ph2: read B n2-3 (4) */                                                \
  _Pragma("unroll") for (int n = 0; n < 2; ++n) {                           \
    b1[n][0] = *reinterpret_cast<const bf16x8*>(bK0 + off + (n + 2) * 2048);\
    b1[n][1] = *reinterpret_cast<const bf16x8*>(bK1 + off + (n + 2) * 2048);\
  }                                                                         \
  __builtin_amdgcn_s_barrier();                                             \
  asm volatile("s_waitcnt lgkmcnt(0)" ::: "memory");                        \
  __builtin_amdgcn_sched_barrier(0);                                        \
  MFMA16(0, 2, b1)                                                          \
  __builtin_amdgcn_s_barrier();                                             \
  CFENCE;                                                                   \
  /* ph3: read A m4-7 (8); stage B(s+2) (B(s) consumed by end-ph2) */       \
  _Pragma("unroll") for (int m = 0; m < 4; ++m) {                           \
    a[m][0] = *reinterpret_cast<const bf16x8*>(aK0 + off + (m + 4) * 2048); \
    a[m][1] = *reinterpret_cast<const bf16x8*>(aK1 + off + (m + 4) * 2048); \
  }                                                                         \
  if (STG) {                                                                \
    _Pragma("unroll") for (int hq = 0; hq < 4; ++hq)                        \
      gl_lds16b(sB[hq] + (size_t)((s) + 2) * 128,                           \
                smem + off + 32768 + hq * 8192 + t * 16);                   \
  }                                                                         \
  __builtin_amdgcn_s_barrier();                                             \
  asm volatile("s_waitcnt lgkmcnt(0)" ::: "memory");                        \
  __builtin_amdgcn_sched_barrier(0);                                        \
  MFMA16(4, 2, b1)                                                          \
  __builtin_amdgcn_s_barrier();                                             \
  CFENCE;                                                                   \
  /* ph4: no reads (b0 reused); stage A(s+2); counted vmcnt */              \
  if (STG) {                                                                \
    _Pragma("unroll") for (int hq = 0; hq < 4; ++hq)                        \
      gl_lds16b(sA[hq] + (size_t)((s) + 2) * 128,                           \
                smem + off + hq * 8192 + t * 16);                           \
  }                                                                         \
  if ((VMW) == 8) asm volatile("s_waitcnt vmcnt(8)" ::: "memory");          \
  else if ((VMW) == 0) asm volatile("s_waitcnt vmcnt(0)" ::: "memory");     \
  __builtin_amdgcn_s_barrier();                                             \
  __builtin_amdgcn_sched_barrier(0);                                        \
  MFMA16(4, 0, b0)                                                          \
  __builtin_amdgcn_s_barrier();                                             \
  CFENCE;                                                                   \
} while (0)

  for (int it = 0; it < 63; ++it) {
    KSTEP(0, 2 * it, true, 8);
    KSTEP(1, 2 * it + 1, true, 8);
  }
  KSTEP(0, 126, false, 0);
  KSTEP(1, 127, false, -1);

#undef KSTEP
#undef MFMA16

  // ---- epilogue: C/D map col=lane&15, row=fq*4+j (verified R1/R2)
  const int rb = bi * 256 + wr * 128;
  const int cb = bj * 256 + wc * 64;
#pragma unroll
  for (int m = 0; m < 8; ++m) {
    const int r0 = rb + m * 16 + fq * 4;
#pragma unroll
    for (int n = 0; n < 4; ++n) {
      const int c = cb + n * 16 + fr;
#pragma unroll
      for (int j = 0; j < 4; ++j)
        C[(size_t)(r0 + j) * N_DIM + c] = acc[m][n][j];
    }
  }
}

extern "C" void kernel_launch(void* const* d_in, const int* in_sizes, int n_in,
                              void* d_out, int out_size, void* d_ws, size_t ws_size,
                              hipStream_t stream) {
  const float* A = (const float*)d_in[0];
  float* C = (float*)d_out;
  ushort* At = (ushort*)d_ws;  // 64 MiB

  transpose_convert<<<dim3((M_DIM / 64) * (N_DIM / 64)), 256, 0, stream>>>(A, At);
  gram8<<<dim3(16 * 16), 512, 0, stream>>>(At, C);
}